// Round 3
// baseline (120.256 us; speedup 1.0000x reference)
//
#include <hip/hip_runtime.h>

#define NODES 512
#define WORDS 16          // 512 bits / 32
#define NBATCH 32
#define SENTINEL 11       // MAX_DISTANCE + 1
#define NEMB 12           // MAX_DISTANCE + 2
#define NOUT 8
#define G 4               // sources per BFS block

// ---------------------------------------------------------------------------
// Kernel A: pack adjacency bits. One thread per element of A.
// bit(b,i,j) = (A[b,i,j] > 0.5) && mask[b,i] && mask[b,j]
// ---------------------------------------------------------------------------
__global__ void __launch_bounds__(256)
pack_bits(const float* __restrict__ A, const int* __restrict__ mask,
          unsigned int* __restrict__ bitA) {
    size_t tid = (size_t)blockIdx.x * 256 + threadIdx.x;
    int j = (int)(tid & 511);
    int i = (int)((tid >> 9) & 511);
    int b = (int)(tid >> 18);
    float a = A[tid];
    bool bit = (a > 0.5f) && (mask[b * NODES + i] != 0) && (mask[b * NODES + j] != 0);
    unsigned long long bal = __ballot(bit);
    if ((threadIdx.x & 63) == 0) {
        size_t w = tid >> 5;
        bitA[w]     = (unsigned int)bal;
        bitA[w + 1] = (unsigned int)(bal >> 32);
    }
}

// ---------------------------------------------------------------------------
// Kernel B: symmetrize: adj[b,i,w] |= transpose bits.
// ---------------------------------------------------------------------------
__global__ void __launch_bounds__(256)
symmetrize(const unsigned int* __restrict__ bitA, unsigned int* __restrict__ adjb) {
    int tid = blockIdx.x * 256 + threadIdx.x;   // total B*N*WORDS = 262144
    int w = tid & 15;
    int i = (tid >> 4) & 511;
    int b = tid >> 13;
    const unsigned int* base = bitA + (size_t)b * NODES * WORDS;
    unsigned int word = base[i * WORDS + w];
    unsigned int t = 0;
    int iw = i >> 5, ib = i & 31;
#pragma unroll
    for (int k = 0; k < 32; ++k) {
        t |= ((base[(32 * w + k) * WORDS + iw] >> ib) & 1u) << k;
    }
    adjb[tid] = word | t;
}

// ---------------------------------------------------------------------------
// Kernel C: bitset BFS -> int8 distance matrix. Block = (source group, batch),
// 512 threads; thread j holds symmetric adjacency row j in 16 VGPRs and
// serves G=4 sources (amortizes the row load). Frontiers in LDS, rebuilt per
// hop via per-wave __ballot. Early exit via per-wave any-flags in LDS
// (no __syncthreads_or -> no LDS atomic serialization). 2 barriers/iter.
// ---------------------------------------------------------------------------
__global__ void __launch_bounds__(512)
bfs_dist(const unsigned int* __restrict__ adjb, const int* __restrict__ mask,
         unsigned char* __restrict__ dist8) {
    const int i0 = blockIdx.x * G;
    const int b = blockIdx.y;
    const int j = threadIdx.x;

    __shared__ unsigned int s_f[G][WORDS];
    __shared__ unsigned int s_any[8];

    // adjacency row j (64 B)
    const uint4* rowp = (const uint4*)(adjb + ((size_t)b * NODES + j) * WORDS);
    unsigned int adjrow[WORDS];
    uint4 r0 = rowp[0], r1 = rowp[1], r2 = rowp[2], r3 = rowp[3];
    adjrow[0] = r0.x; adjrow[1] = r0.y; adjrow[2]  = r0.z; adjrow[3]  = r0.w;
    adjrow[4] = r1.x; adjrow[5] = r1.y; adjrow[6]  = r1.z; adjrow[7]  = r1.w;
    adjrow[8] = r2.x; adjrow[9] = r2.y; adjrow[10] = r2.z; adjrow[11] = r2.w;
    adjrow[12] = r3.x; adjrow[13] = r3.y; adjrow[14] = r3.z; adjrow[15] = r3.w;

    if (j < G * WORDS) {
        int s = j >> 4, w = j & 15;
        int i = i0 + s;
        bool v = (mask[b * NODES + i] != 0);
        s_f[s][w] = (v && (i >> 5) == w) ? (1u << (i & 31)) : 0u;
    }

    int dist[G];
    bool reach[G];
#pragma unroll
    for (int s = 0; s < G; ++s) {
        int i = i0 + s;
        bool v = (mask[b * NODES + i] != 0);
        reach[s] = (j == i) && v;
        dist[s] = reach[s] ? 0 : SENTINEL;
    }
    __syncthreads();

    for (int t = 1; t <= 10; ++t) {
        bool newly[G];
#pragma unroll
        for (int s = 0; s < G; ++s) {
            unsigned int hit = 0;
#pragma unroll
            for (int w = 0; w < WORDS; ++w) hit |= adjrow[w] & s_f[s][w];
            newly[s] = (hit != 0) && !reach[s];
        }
        __syncthreads();                       // all reads of s_f done
        unsigned long long anyb = 0;
#pragma unroll
        for (int s = 0; s < G; ++s) {
            unsigned long long bal = __ballot(newly[s]);
            anyb |= bal;
            if ((j & 63) == 0) {
                int wv = j >> 6;
                s_f[s][2 * wv]     = (unsigned int)bal;
                s_f[s][2 * wv + 1] = (unsigned int)(bal >> 32);
            }
        }
        if ((j & 63) == 0) s_any[j >> 6] = (anyb != 0ull) ? 1u : 0u;
#pragma unroll
        for (int s = 0; s < G; ++s)
            if (newly[s]) { reach[s] = true; dist[s] = t; }
        __syncthreads();                       // new frontier + any flags ready
        unsigned int any = 0;
#pragma unroll
        for (int wv = 0; wv < 8; ++wv) any |= s_any[wv];
        if (!any) break;
    }

#pragma unroll
    for (int s = 0; s < G; ++s)
        dist8[((size_t)b * NODES + (i0 + s)) * NODES + j] = (unsigned char)dist[s];
}

// ---------------------------------------------------------------------------
// Kernel D: pure streaming expansion. One float4 (half an embedding row) per
// thread: lane-contiguous 16 B chunks -> 1 KB per store instruction per wave.
// emb is 384 B -> L1-resident gather, no LDS, no barrier.
// ---------------------------------------------------------------------------
__global__ void __launch_bounds__(256)
expand(const unsigned char* __restrict__ dist8, const float* __restrict__ emb,
       float4* __restrict__ out) {
    size_t tid = (size_t)blockIdx.x * 256 + threadIdx.x;   // B*N*N*2 total
    int d = dist8[tid >> 1];
    out[tid] = ((const float4*)emb)[2 * d + (int)(tid & 1)];
}

// ---------------------------------------------------------------------------
extern "C" void kernel_launch(void* const* d_in, const int* in_sizes, int n_in,
                              void* d_out, int out_size, void* d_ws, size_t ws_size,
                              hipStream_t stream) {
    const float* adjacency = (const float*)d_in[0];
    const int* node_mask = (const int*)d_in[1];   // bool -> int32 on upload
    const float* emb = (const float*)d_in[2];
    float* out = (float*)d_out;

    unsigned int* bitA = (unsigned int*)d_ws;                       // 1 MB
    unsigned int* adjb = bitA + (size_t)NBATCH * NODES * WORDS;     // 1 MB
    unsigned char* dist8 = (unsigned char*)(adjb + (size_t)NBATCH * NODES * WORDS); // 8 MB

    // A: 32*512*512 = 8388608 elements -> 32768 blocks
    pack_bits<<<32768, 256, 0, stream>>>(adjacency, node_mask, bitA);
    // B: 32*512*16 = 262144 words -> 1024 blocks
    symmetrize<<<1024, 256, 0, stream>>>(bitA, adjb);
    // C: one block per (4 sources, batch)
    bfs_dist<<<dim3(NODES / G, NBATCH), 512, 0, stream>>>(adjb, node_mask, dist8);
    // D: B*N*N*2 float4 stores = 16777216 threads -> 65536 blocks
    expand<<<65536, 256, 0, stream>>>(dist8, emb, (float4*)out);
}

// Round 4
// 85.985 us; speedup vs baseline: 1.3986x; 1.3986x over previous
//
#include <hip/hip_runtime.h>

#define NODES 512
#define WORDS 16          // 512 bits / 32
#define NBATCH 32
#define SENTINEL 11       // MAX_DISTANCE + 1
#define NEMB 12           // MAX_DISTANCE + 2
#define NOUT 8
#define G 4               // sources per BFS block

// ---------------------------------------------------------------------------
// K0: pack node_mask (int32 on upload) into bitset maskbits[b*16+w].
// ---------------------------------------------------------------------------
__global__ void __launch_bounds__(256)
mask_pack(const int* __restrict__ mask, unsigned int* __restrict__ maskbits) {
    int tid = blockIdx.x * 256 + threadIdx.x;   // 32*512 = 16384 total
    bool bit = mask[tid] != 0;
    unsigned long long bal = __ballot(bit);
    if ((threadIdx.x & 63) == 0) {
        int w = tid >> 5;                        // even for lane 0
        maskbits[w]     = (unsigned int)bal;
        maskbits[w + 1] = (unsigned int)(bal >> 32);
    }
}

// ---------------------------------------------------------------------------
// K1: pack adjacency bits, one u32 WORD per thread (32 elements, 8x float4
// = 128 B/lane -> fully vectorized reads; no ballot, no per-element mask
// loads: row mask is one scalar, column mask is one maskbits word).
// ---------------------------------------------------------------------------
__global__ void __launch_bounds__(256)
pack_bits(const float* __restrict__ A, const int* __restrict__ mask,
          const unsigned int* __restrict__ maskbits,
          unsigned int* __restrict__ bitA) {
    int tid = blockIdx.x * 256 + threadIdx.x;   // 32*512*16 = 262144 words
    int w = tid & 15;
    int i = (tid >> 4) & 511;
    int b = tid >> 13;
    const float4* p = (const float4*)(A + (size_t)tid * 32);
    unsigned int bits = 0;
#pragma unroll
    for (int q = 0; q < 8; ++q) {
        float4 v = p[q];
        bits |= (v.x > 0.5f ? 1u : 0u) << (4 * q);
        bits |= (v.y > 0.5f ? 1u : 0u) << (4 * q + 1);
        bits |= (v.z > 0.5f ? 1u : 0u) << (4 * q + 2);
        bits |= (v.w > 0.5f ? 1u : 0u) << (4 * q + 3);
    }
    unsigned int mw = maskbits[b * WORDS + w];
    bool rv = mask[b * NODES + i] != 0;
    bitA[tid] = rv ? (bits & mw) : 0u;
}

// ---------------------------------------------------------------------------
// K2: symmetrize: adj[b,i,w] |= transpose bits (all L2-resident, 1 MB).
// ---------------------------------------------------------------------------
__global__ void __launch_bounds__(256)
symmetrize(const unsigned int* __restrict__ bitA, unsigned int* __restrict__ adjb) {
    int tid = blockIdx.x * 256 + threadIdx.x;   // total B*N*WORDS = 262144
    int w = tid & 15;
    int i = (tid >> 4) & 511;
    int b = tid >> 13;
    const unsigned int* base = bitA + (size_t)b * NODES * WORDS;
    unsigned int word = base[i * WORDS + w];
    unsigned int t = 0;
    int iw = i >> 5, ib = i & 31;
#pragma unroll
    for (int k = 0; k < 32; ++k) {
        t |= ((base[(32 * w + k) * WORDS + iw] >> ib) & 1u) << k;
    }
    adjb[tid] = word | t;
}

// ---------------------------------------------------------------------------
// K3: fused bitset-BFS + embedding store. Block = (group of G=4 sources, b),
// 512 threads; thread j holds symmetric adjacency row j (16 VGPRs) and serves
// all 4 sources. Frontiers in LDS via per-wave __ballot; early exit via
// per-wave any-flags (2 barriers/iter). Epilogue redistributes dist through
// LDS so every store instruction is 64 lane-contiguous float4s (1 KB/wave).
// ---------------------------------------------------------------------------
__global__ void __launch_bounds__(512)
bfs_store(const unsigned int* __restrict__ adjb, const int* __restrict__ mask,
          const float* __restrict__ emb, float4* __restrict__ out4) {
    const int i0 = blockIdx.x * G;
    const int b = blockIdx.y;
    const int j = threadIdx.x;

    __shared__ unsigned int s_f[G][WORDS];
    __shared__ unsigned int s_any[8];
    __shared__ unsigned char s_dist[G][NODES];
    __shared__ __align__(16) float s_emb[NEMB * NOUT];

    if (j < NEMB * NOUT) s_emb[j] = emb[j];

    // adjacency row j (64 B)
    const uint4* rowp = (const uint4*)(adjb + ((size_t)b * NODES + j) * WORDS);
    unsigned int adjrow[WORDS];
    uint4 r0 = rowp[0], r1 = rowp[1], r2 = rowp[2], r3 = rowp[3];
    adjrow[0] = r0.x; adjrow[1] = r0.y; adjrow[2]  = r0.z; adjrow[3]  = r0.w;
    adjrow[4] = r1.x; adjrow[5] = r1.y; adjrow[6]  = r1.z; adjrow[7]  = r1.w;
    adjrow[8] = r2.x; adjrow[9] = r2.y; adjrow[10] = r2.z; adjrow[11] = r2.w;
    adjrow[12] = r3.x; adjrow[13] = r3.y; adjrow[14] = r3.z; adjrow[15] = r3.w;

    if (j < G * WORDS) {
        int s = j >> 4, w = j & 15;
        int i = i0 + s;
        bool v = (mask[b * NODES + i] != 0);
        s_f[s][w] = (v && (i >> 5) == w) ? (1u << (i & 31)) : 0u;
    }

    int dist[G];
    bool reach[G];
#pragma unroll
    for (int s = 0; s < G; ++s) {
        int i = i0 + s;
        bool v = (mask[b * NODES + i] != 0);
        reach[s] = (j == i) && v;
        dist[s] = reach[s] ? 0 : SENTINEL;
    }
    __syncthreads();

    for (int t = 1; t <= 10; ++t) {
        bool newly[G];
#pragma unroll
        for (int s = 0; s < G; ++s) {
            unsigned int hit = 0;
#pragma unroll
            for (int w = 0; w < WORDS; ++w) hit |= adjrow[w] & s_f[s][w];
            newly[s] = (hit != 0) && !reach[s];
        }
        __syncthreads();                       // all reads of s_f done
        unsigned long long anyb = 0;
#pragma unroll
        for (int s = 0; s < G; ++s) {
            unsigned long long bal = __ballot(newly[s]);
            anyb |= bal;
            if ((j & 63) == 0) {
                int wv = j >> 6;
                s_f[s][2 * wv]     = (unsigned int)bal;
                s_f[s][2 * wv + 1] = (unsigned int)(bal >> 32);
            }
        }
        if ((j & 63) == 0) s_any[j >> 6] = (anyb != 0ull) ? 1u : 0u;
#pragma unroll
        for (int s = 0; s < G; ++s)
            if (newly[s]) { reach[s] = true; dist[s] = t; }
        __syncthreads();                       // new frontier + any flags ready
        unsigned int any = 0;
#pragma unroll
        for (int wv = 0; wv < 8; ++wv) any |= s_any[wv];
        if (!any) break;
    }

    // Epilogue: redistribute dist via LDS; 8 perfectly-contiguous stores.
#pragma unroll
    for (int s = 0; s < G; ++s) s_dist[s][j] = (unsigned char)dist[s];
    __syncthreads();   // also orders the s_emb writes from kernel start

    const float4* e4 = (const float4*)s_emb;
#pragma unroll
    for (int s = 0; s < G; ++s) {
        size_t rb = ((size_t)b * NODES + (i0 + s)) * (NODES * NOUT / 4); // 1024 f4/row
#pragma unroll
        for (int h = 0; h < 2; ++h) {
            int d = s_dist[s][(h << 8) + (j >> 1)];   // dist of column (h*512+j)/2
            out4[rb + h * NODES + j] = e4[2 * d + (j & 1)];
        }
    }
}

// ---------------------------------------------------------------------------
extern "C" void kernel_launch(void* const* d_in, const int* in_sizes, int n_in,
                              void* d_out, int out_size, void* d_ws, size_t ws_size,
                              hipStream_t stream) {
    const float* adjacency = (const float*)d_in[0];
    const int* node_mask = (const int*)d_in[1];   // bool -> int32 on upload
    const float* emb = (const float*)d_in[2];
    float4* out4 = (float4*)d_out;

    unsigned int* maskbits = (unsigned int*)d_ws;                   // 2 KB
    unsigned int* bitA = maskbits + 512;                            // 1 MB
    unsigned int* adjb = bitA + (size_t)NBATCH * NODES * WORDS;     // 1 MB

    // K0: 16384 mask elements -> 64 blocks
    mask_pack<<<64, 256, 0, stream>>>(node_mask, maskbits);
    // K1: 262144 words -> 1024 blocks (each thread: 32 adjacency elements)
    pack_bits<<<1024, 256, 0, stream>>>(adjacency, node_mask, maskbits, bitA);
    // K2: 262144 words -> 1024 blocks
    symmetrize<<<1024, 256, 0, stream>>>(bitA, adjb);
    // K3: one block per (4 sources, batch); fused BFS + store
    bfs_store<<<dim3(NODES / G, NBATCH), 512, 0, stream>>>(adjb, node_mask, emb, out4);
}